// Round 1
// baseline (5724.770 us; speedup 1.0000x reference)
//
#include <hip/hip_runtime.h>
#include <math.h>

// Problem constants
constexpr int kB = 16, kL = 512, kS = 1024, kD = 512, kH = 8, kM = 64;
constexpr int kDFF = 2048, kCO = 512;

// ---------------------------------------------------------------------------
// Generic fp32 GEMM:  C[r,n] = op( sum_c A[r,c]*W[n,c] + bias + resid (+C) )
// A row-major (R x K), W row-major (N x K)  (i.e. X @ W.T)
// flags: 1=relu, 2=accumulate into C, 4=circular row shift (rows are (b,l), l in [0,512))
// ---------------------------------------------------------------------------
__global__ __launch_bounds__(256) void gemm_nt(
    const float* __restrict__ A, const float* __restrict__ W,
    const float* __restrict__ bias, const float* __restrict__ resid,
    float* __restrict__ Cmat, int R, int N, int K, int flags, int shift)
{
    __shared__ float As[16][132];
    __shared__ float Bs[16][132];
    const int tid = threadIdx.x;
    const int tx = tid & 15, ty = tid >> 4;
    const int r0 = blockIdx.y * 128, n0 = blockIdx.x * 128;

    float acc[8][8];
#pragma unroll
    for (int u = 0; u < 8; ++u)
#pragma unroll
        for (int v = 0; v < 8; ++v) acc[u][v] = 0.f;

    // precompute source rows (circular shift for circ-conv GEMMs)
    int arow[8];
#pragma unroll
    for (int rep = 0; rep < 8; ++rep) {
        int gr = r0 + (tid >> 4) + rep * 16;
        if (flags & 4) {
            int bb = gr >> 9, ll = gr & 511;
            gr = (bb << 9) | ((ll + shift) & 511);
        }
        arow[rep] = gr;
    }
    const int kk = tid & 15;

    for (int k0 = 0; k0 < K; k0 += 16) {
#pragma unroll
        for (int rep = 0; rep < 8; ++rep) {
            int i = (tid >> 4) + rep * 16;
            As[kk][i] = A[(size_t)arow[rep] * K + k0 + kk];
        }
#pragma unroll
        for (int rep = 0; rep < 8; ++rep) {
            int j = (tid >> 4) + rep * 16;
            int gn = n0 + j;
            Bs[kk][j] = (gn < N) ? W[(size_t)gn * K + k0 + kk] : 0.f;
        }
        __syncthreads();
#pragma unroll
        for (int k = 0; k < 16; ++k) {
            float4 a0 = *(const float4*)&As[k][ty * 4];
            float4 a1 = *(const float4*)&As[k][64 + ty * 4];
            float4 b0 = *(const float4*)&Bs[k][tx * 4];
            float4 b1 = *(const float4*)&Bs[k][64 + tx * 4];
            float av[8] = {a0.x, a0.y, a0.z, a0.w, a1.x, a1.y, a1.z, a1.w};
            float bv[8] = {b0.x, b0.y, b0.z, b0.w, b1.x, b1.y, b1.z, b1.w};
#pragma unroll
            for (int u = 0; u < 8; ++u)
#pragma unroll
                for (int v = 0; v < 8; ++v) acc[u][v] += av[u] * bv[v];
        }
        __syncthreads();
    }

#pragma unroll
    for (int u = 0; u < 8; ++u) {
        int gr = r0 + ((u < 4) ? (ty * 4 + u) : (64 + ty * 4 + u - 4));
#pragma unroll
        for (int v = 0; v < 8; ++v) {
            int gn = n0 + ((v < 4) ? (tx * 4 + v) : (64 + tx * 4 + v - 4));
            if (gn < N) {
                float val = acc[u][v];
                if (bias) val += bias[gn];
                if (resid) val += resid[(size_t)gr * N + gn];
                if (flags & 2) val += Cmat[(size_t)gr * N + gn];
                if (flags & 1) val = fmaxf(val, 0.f);
                Cmat[(size_t)gr * N + gn] = val;
            }
        }
    }
}

// ---------------------------------------------------------------------------
// Forward DFT, first kM modes:  F[b,m,d] = sum_l A[b,l,d] * e^{-2*pi*i*m*l/N}
// A is (B, N, D). Output (B, kM, D) normal layout, or [d][b][m] when transposed
// (the transposed layout feeds feb_mode coalesced). 4 modes per block.
// ---------------------------------------------------------------------------
__global__ __launch_bounds__(512) void dft_fwd(
    const float* __restrict__ A, float* __restrict__ Fr, float* __restrict__ Fi,
    int N, int transposed)
{
    __shared__ float t0c[1024], t0s[1024], stc[1024], sts[1024];
    const int blk = blockIdx.x;
    const int b = blk >> 4;                 // 16 mode-groups
    const int m0 = (blk & 15) * 4;
    const int tid = threadIdx.x;

    for (int l = tid; l < N; l += 512) {
        int ph0 = (m0 * l) % N;
        float a0 = -6.283185307179586f * (float)ph0 / (float)N;
        float s_, c_;
        sincosf(a0, &s_, &c_);
        t0c[l] = c_; t0s[l] = s_;
        float a1 = -6.283185307179586f * (float)l / (float)N;
        sincosf(a1, &s_, &c_);
        stc[l] = c_; sts[l] = s_;
    }
    __syncthreads();

    const int d = tid;  // 512 threads = kD
    float fr[4] = {0, 0, 0, 0}, fi[4] = {0, 0, 0, 0};
    const float* Ab = A + (size_t)b * N * kD + d;
    for (int l = 0; l < N; ++l) {
        float a = Ab[(size_t)l * kD];
        float cr = t0c[l], ci = t0s[l];
        float sc = stc[l], ssn = sts[l];
#pragma unroll
        for (int mm = 0; mm < 4; ++mm) {
            fr[mm] += a * cr;
            fi[mm] += a * ci;
            float nr = cr * sc - ci * ssn;
            ci = cr * ssn + ci * sc;
            cr = nr;
        }
    }
#pragma unroll
    for (int mm = 0; mm < 4; ++mm) {
        if (transposed) {
            size_t idx = ((size_t)d * kB + b) * kM + m0 + mm;
            Fr[idx] = fr[mm]; Fi[idx] = fi[mm];
        } else {
            size_t idx = ((size_t)b * kM + m0 + mm) * kD + d;
            Fr[idx] = fr[mm]; Fi[idx] = fi[mm];
        }
    }
}

// ---------------------------------------------------------------------------
// FEB per-mode complex contraction: om[b,m,e] = sum_d qf[b,m,d] * W[d,e,m]
// qf given in transposed layout [d][b][m]; W strided (d*kD+e)*kM+m (coalesced in m).
// Block: 2 e-columns, 128 threads = (ee:2 x m:64). om written (B,kM,kD).
// ---------------------------------------------------------------------------
__global__ __launch_bounds__(128) void feb_mode(
    const float* __restrict__ qtr, const float* __restrict__ qti,
    const float* __restrict__ wr, const float* __restrict__ wi,
    float* __restrict__ omr, float* __restrict__ omi)
{
    __shared__ float sqr[4][16][64], sqi[4][16][64];  // [dd][b][m]
    const int e0 = blockIdx.x * 2;
    const int mm = threadIdx.x & 63, ee = threadIdx.x >> 6;
    const int e = e0 + ee;
    float ar[16], ai[16];
#pragma unroll
    for (int b_ = 0; b_ < 16; ++b_) { ar[b_] = 0.f; ai[b_] = 0.f; }

    for (int d0 = 0; d0 < kD; d0 += 4) {
        __syncthreads();
        for (int rep = 0; rep < 32; ++rep) {
            int idx = threadIdx.x + rep * 128;       // 0..4095
            int m_ = idx & 63, b_ = (idx >> 6) & 15, dd_ = idx >> 10;
            size_t g = ((size_t)(d0 + dd_) * kB + b_) * kM + m_;
            sqr[dd_][b_][m_] = qtr[g];
            sqi[dd_][b_][m_] = qti[g];
        }
        __syncthreads();
#pragma unroll
        for (int dd = 0; dd < 4; ++dd) {
            size_t wofs = ((size_t)(d0 + dd) * kD + e) * kM + mm;
            float wrv = wr[wofs];
            float wiv = wi[wofs];
#pragma unroll
            for (int b_ = 0; b_ < 16; ++b_) {
                float qr = sqr[dd][b_][mm], qi = sqi[dd][b_][mm];
                ar[b_] += qr * wrv - qi * wiv;
                ai[b_] += qr * wiv + qi * wrv;
            }
        }
    }
#pragma unroll
    for (int b_ = 0; b_ < 16; ++b_) {
        size_t o = ((size_t)b_ * kM + mm) * kD + e;
        omr[o] = ar[b_];
        omi[o] = ai[b_];
    }
}

// ---------------------------------------------------------------------------
// Inverse real DFT (modes 0..63, output length 512):
// out[b,l,e] = (1/512)*( Xr[0] + 2*sum_{m=1..63} (Xr cos(2pi m l/512) - Xi sin) )
// (imag of bin 0 ignored -- numpy irfft semantics). Optional residual add.
// Block: (b, 16 l's), 512 threads over e.
// ---------------------------------------------------------------------------
__global__ __launch_bounds__(512) void irdft(
    const float* __restrict__ omr, const float* __restrict__ omi,
    const float* __restrict__ resid, float* __restrict__ out)
{
    __shared__ float tc[64][16], tsn[64][16];
    const int blk = blockIdx.x;
    const int b = blk >> 5;
    const int l0 = (blk & 31) << 4;
    const int tid = threadIdx.x;

    for (int idx = tid; idx < 1024; idx += 512) {
        int m_ = idx >> 4, ll = idx & 15;
        int ph = (m_ * (l0 + ll)) & 511;
        float ang = 6.283185307179586f * (float)ph / 512.0f;
        float s_, c_;
        sincosf(ang, &s_, &c_);
        tc[m_][ll] = c_; tsn[m_][ll] = s_;
    }
    __syncthreads();

    const int e = tid;
    float acc[16];
    float r0 = omr[((size_t)b * kM) * kD + e];
#pragma unroll
    for (int ll = 0; ll < 16; ++ll) acc[ll] = r0;
    for (int m_ = 1; m_ < 64; ++m_) {
        float r = 2.f * omr[((size_t)b * kM + m_) * kD + e];
        float i_ = 2.f * omi[((size_t)b * kM + m_) * kD + e];
#pragma unroll
        for (int ll = 0; ll < 16; ++ll) acc[ll] += r * tc[m_][ll] - i_ * tsn[m_][ll];
    }
    const float inv = 1.0f / 512.0f;
#pragma unroll
    for (int ll = 0; ll < 16; ++ll) {
        size_t o = ((size_t)b * kL + l0 + ll) * kD + e;
        float v = acc[ll] * inv;
        if (resid) v += resid[o];
        out[o] = v;
    }
}

// ---------------------------------------------------------------------------
// Spectral cross attention, one block per (b,h):
//   S[i,j] = sum_dd qfr*kfr + qfi*kfi ; softmax over j ; of = S @ (vfr, vfi)
// qf: (B,kM,kD) layout, head h occupies columns h*64..h*64+63.
// ---------------------------------------------------------------------------
__global__ __launch_bounds__(256) void spectral_attn(
    const float* __restrict__ qfr, const float* __restrict__ qfi,
    const float* __restrict__ kfr, const float* __restrict__ kfi,
    const float* __restrict__ vfr, const float* __restrict__ vfi,
    float* __restrict__ omr, float* __restrict__ omi)
{
    __shared__ float kr[64][65], ki[64][65], sat[64][65];
    const int b = blockIdx.x >> 3, h = blockIdx.x & 7;
    const int tid = threadIdx.x;
    const int dbase = h * 64;

    for (int idx = tid; idx < 4096; idx += 256) {
        int j = idx >> 6, dd = idx & 63;
        kr[j][dd] = kfr[((size_t)b * kM + j) * kD + dbase + dd];
        ki[j][dd] = kfi[((size_t)b * kM + j) * kD + dbase + dd];
    }
    __syncthreads();

    const int i_ = tid >> 2, jg = tid & 3;
    float s[16];
#pragma unroll
    for (int jj = 0; jj < 16; ++jj) s[jj] = 0.f;
    const float* qrp = qfr + ((size_t)b * kM + i_) * kD + dbase;
    const float* qip = qfi + ((size_t)b * kM + i_) * kD + dbase;
    for (int dd = 0; dd < 64; ++dd) {
        float qr = qrp[dd], qi = qip[dd];
#pragma unroll
        for (int jj = 0; jj < 16; ++jj) {
            int j = jg * 16 + jj;
            s[jj] += qr * kr[j][dd] + qi * ki[j][dd];
        }
    }
    // softmax across the row (4 lanes x 16 each)
    float mx = s[0];
#pragma unroll
    for (int jj = 1; jj < 16; ++jj) mx = fmaxf(mx, s[jj]);
    mx = fmaxf(mx, __shfl_xor(mx, 1));
    mx = fmaxf(mx, __shfl_xor(mx, 2));
    float sum = 0.f;
#pragma unroll
    for (int jj = 0; jj < 16; ++jj) { s[jj] = expf(s[jj] - mx); sum += s[jj]; }
    sum += __shfl_xor(sum, 1);
    sum += __shfl_xor(sum, 2);
    float rinv = 1.0f / sum;
#pragma unroll
    for (int jj = 0; jj < 16; ++jj) sat[i_][jg * 16 + jj] = s[jj] * rinv;
    __syncthreads();

    const int dd = tid & 63, ig = tid >> 6;
    float ar[16], ai[16];
#pragma unroll
    for (int ii = 0; ii < 16; ++ii) { ar[ii] = 0.f; ai[ii] = 0.f; }
    for (int j = 0; j < 64; ++j) {
        float vr = vfr[((size_t)b * kM + j) * kD + dbase + dd];
        float vi = vfi[((size_t)b * kM + j) * kD + dbase + dd];
#pragma unroll
        for (int ii = 0; ii < 16; ++ii) {
            float a = sat[ig * 16 + ii][j];
            ar[ii] += a * vr;
            ai[ii] += a * vi;
        }
    }
#pragma unroll
    for (int ii = 0; ii < 16; ++ii) {
        size_t o = ((size_t)b * kM + ig * 16 + ii) * kD + dbase + dd;
        omr[o] = ar[ii];
        omi[o] = ai[ii];
    }
}

// ---------------------------------------------------------------------------
// MoE decomposition epilogue: softmax gate over 3 logits, 3 avg-pools (k=3,5,7,
// zero-padded ends, always /k), trend mix, x - trend.
// ---------------------------------------------------------------------------
__global__ __launch_bounds__(256) void decomp_apply(
    const float* __restrict__ x, const float* __restrict__ logits,
    float* __restrict__ xout, float* __restrict__ tout)
{
    int idx = blockIdx.x * 256 + threadIdx.x;
    if (idx >= kB * kL * kD) return;
    int d = idx & 511;
    int l = (idx >> 9) & 511;
    int b = idx >> 18;
    const float* lg = logits + ((size_t)b * kL + l) * 3;
    float g0 = lg[0], g1 = lg[1], g2 = lg[2];
    float m = fmaxf(g0, fmaxf(g1, g2));
    float e0 = expf(g0 - m), e1 = expf(g1 - m), e2 = expf(g2 - m);
    float inv = 1.0f / (e0 + e1 + e2);
    g0 = e0 * inv; g1 = e1 * inv; g2 = e2 * inv;

    const float* xb = x + (size_t)b * kL * kD + d;
    float v[7];
#pragma unroll
    for (int j = 0; j < 7; ++j) {
        int ls = l + j - 3;
        v[j] = (ls >= 0 && ls < kL) ? xb[(size_t)ls * kD] : 0.f;
    }
    float s3 = (v[2] + v[3] + v[4]) * (1.0f / 3.0f);
    float s5 = (v[1] + v[2] + v[3] + v[4] + v[5]) * 0.2f;
    float s7 = (v[0] + v[1] + v[2] + v[3] + v[4] + v[5] + v[6]) * (1.0f / 7.0f);
    float trend = g0 * s3 + g1 * s5 + g2 * s7;
    xout[idx] = v[3] - trend;
    tout[idx] = trend;
}

// ---------------------------------------------------------------------------
// Repack conv weights p[o,d,j] -> pk[t][j][o][d]
// ---------------------------------------------------------------------------
__global__ void repack_p(const float* __restrict__ p1, const float* __restrict__ p2,
                         const float* __restrict__ p3, float* __restrict__ pk)
{
    int idx = blockIdx.x * 256 + threadIdx.x;
    if (idx >= 3 * 3 * kCO * kD) return;
    int d = idx % kD;
    int oc = (idx / kD) % kCO;
    int j = (idx / (kD * kCO)) % 3;
    int t = idx / (3 * kCO * kD);
    const float* p = (t == 0) ? p1 : (t == 1) ? p2 : p3;
    pk[idx] = p[(size_t)oc * kD * 3 + (size_t)d * 3 + j];
}

// ---------------------------------------------------------------------------
extern "C" void kernel_launch(void* const* d_in, const int* in_sizes, int n_in,
                              void* d_out, int out_size, void* d_ws, size_t ws_size,
                              hipStream_t stream)
{
    const float* x_in   = (const float*)d_in[0];
    const float* cross  = (const float*)d_in[1];
    const float* feb_wr = (const float*)d_in[2];
    const float* feb_wi = (const float*)d_in[3];
    const float* wq = (const float*)d_in[4];
    const float* bq = (const float*)d_in[5];
    const float* wk = (const float*)d_in[6];
    const float* bk = (const float*)d_in[7];
    const float* wv = (const float*)d_in[8];
    const float* bv = (const float*)d_in[9];
    const float* wo = (const float*)d_in[10];
    const float* bo = (const float*)d_in[11];
    const float* w_ff1 = (const float*)d_in[12];
    const float* w_ff2 = (const float*)d_in[13];
    const float* d1_w1 = (const float*)d_in[14];
    const float* d1_b1 = (const float*)d_in[15];
    const float* d1_w2 = (const float*)d_in[16];
    const float* d1_b2 = (const float*)d_in[17];
    const float* d2_w1 = (const float*)d_in[18];
    const float* d2_b1 = (const float*)d_in[19];
    const float* d2_w2 = (const float*)d_in[20];
    const float* d2_b2 = (const float*)d_in[21];
    const float* d3_w1 = (const float*)d_in[22];
    const float* d3_b1 = (const float*)d_in[23];
    const float* d3_w2 = (const float*)d_in[24];
    const float* d3_b2 = (const float*)d_in[25];
    const float* p1 = (const float*)d_in[26];
    const float* p2 = (const float*)d_in[27];
    const float* p3 = (const float*)d_in[28];

    // workspace layout (floats); total ~46.2M floats ~= 185 MB
    float* ws = (float*)d_ws;
    float* X    = ws;                 // 4194304  (B*L*D)
    float* XT   = ws + 4194304;       // 4194304
    float* Q    = ws + 8388608;       // 4194304   (also reused as GH gate hidden)
    float* KBUF = ws + 12582912;      // 8388608  (B*S*D)  } contiguous 16.78M -> FFN hidden
    float* VBUF = ws + 20971520;      // 8388608           }
    float* T1   = ws + 29360128;      // 4194304
    float* T2   = ws + 33554432;      // 4194304
    float* T3   = ws + 37748736;      // 4194304
    float* QFR  = ws + 41943040;      // 8 x 524288 spectral buffers
    float* QFI  = QFR + 524288;
    float* KFR  = QFI + 524288;
    float* KFI  = KFR + 524288;
    float* VFR  = KFI + 524288;
    float* VFI  = VFR + 524288;
    float* OMR  = VFI + 524288;
    float* OMI  = OMR + 524288;
    float* GH   = Q;                  // gate hidden (B*L*256), only live in decomp phases
    float* GLG  = ws + 46137344;      // 24576 (B*L*3)
    float* PK   = QFR;                // repacked conv weights (2359296), phase G only
    float* HID  = KBUF;               // FFN hidden (B*L*DFF = 16777216), phase E only

    float* outx = (float*)d_out;
    float* outt = outx + 4194304;

    auto gemm = [&](const float* A, const float* W, const float* bias,
                    const float* resid, float* C, int R, int N, int K,
                    int flags, int shift) {
        dim3 g((N + 127) / 128, (R + 127) / 128);
        hipLaunchKernelGGL(gemm_nt, g, dim3(256), 0, stream,
                           A, W, bias, resid, C, R, N, K, flags, shift);
    };

    const int RL = kB * kL;   // 8192
    const int RS = kB * kS;   // 16384

    // ---- Phase A: x = x + fourier_block(x) ----
    hipLaunchKernelGGL(dft_fwd, dim3(256), dim3(512), 0, stream, x_in, QFR, QFI, kL, 1);
    hipLaunchKernelGGL(feb_mode, dim3(256), dim3(128), 0, stream, QFR, QFI, feb_wr, feb_wi, OMR, OMI);
    hipLaunchKernelGGL(irdft, dim3(512), dim3(512), 0, stream, OMR, OMI, x_in, X);

    // ---- Phase B: decomp1 ----
    gemm(X, d1_w1, d1_b1, nullptr, GH, RL, 256, kD, 1, 0);
    gemm(GH, d1_w2, d1_b2, nullptr, GLG, RL, 3, 256, 0, 0);
    hipLaunchKernelGGL(decomp_apply, dim3(16384), dim3(256), 0, stream, X, GLG, XT, T1);
    // current x = XT

    // ---- Phase C: x = x + fourier_cross(x, cross) ----
    gemm(XT, wq, bq, nullptr, Q, RL, kD, kD, 0, 0);
    gemm(cross, wk, bk, nullptr, KBUF, RS, kD, kD, 0, 0);
    gemm(cross, wv, bv, nullptr, VBUF, RS, kD, kD, 0, 0);
    hipLaunchKernelGGL(dft_fwd, dim3(256), dim3(512), 0, stream, Q, QFR, QFI, kL, 0);
    hipLaunchKernelGGL(dft_fwd, dim3(256), dim3(512), 0, stream, KBUF, KFR, KFI, kS, 0);
    hipLaunchKernelGGL(dft_fwd, dim3(256), dim3(512), 0, stream, VBUF, VFR, VFI, kS, 0);
    hipLaunchKernelGGL(spectral_attn, dim3(128), dim3(256), 0, stream,
                       QFR, QFI, KFR, KFI, VFR, VFI, OMR, OMI);
    hipLaunchKernelGGL(irdft, dim3(512), dim3(512), 0, stream, OMR, OMI, (const float*)nullptr, Q);
    gemm(Q, wo, bo, XT, X, RL, kD, kD, 0, 0);
    // current x = X

    // ---- Phase D: decomp2 ----
    gemm(X, d2_w1, d2_b1, nullptr, GH, RL, 256, kD, 1, 0);
    gemm(GH, d2_w2, d2_b2, nullptr, GLG, RL, 3, 256, 0, 0);
    hipLaunchKernelGGL(decomp_apply, dim3(16384), dim3(256), 0, stream, X, GLG, XT, T2);
    // current x = XT

    // ---- Phase E: FFN ----
    gemm(XT, w_ff1, nullptr, nullptr, HID, RL, kDFF, kD, 1, 0);
    gemm(HID, w_ff2, nullptr, XT, X, RL, kD, kDFF, 0, 0);
    // current x = X (= x + y)

    // ---- Phase F: decomp3 (final x straight to d_out) ----
    gemm(X, d3_w1, d3_b1, nullptr, GH, RL, 256, kD, 1, 0);
    gemm(GH, d3_w2, d3_b2, nullptr, GLG, RL, 3, 256, 0, 0);
    hipLaunchKernelGGL(decomp_apply, dim3(16384), dim3(256), 0, stream, X, GLG, outx, T3);

    // ---- Phase G: residual_trend = sum_t circ_conv(T_t, p_t) ----
    hipLaunchKernelGGL(repack_p, dim3(9216), dim3(256), 0, stream, p1, p2, p3, PK);
    const float* Ts[3] = {T1, T2, T3};
    for (int t = 0; t < 3; ++t) {
        for (int j = 0; j < 3; ++j) {
            const float* Wp = PK + (size_t)t * 3 * kCO * kD + (size_t)j * kCO * kD;
            int flags = 4 | ((t == 0 && j == 0) ? 0 : 2);
            gemm(Ts[t], Wp, nullptr, nullptr, outt, RL, kCO, kD, flags, j - 1);
        }
    }
    (void)in_sizes; (void)n_in; (void)out_size; (void)ws_size;
}

// Round 3
// 1110.141 us; speedup vs baseline: 5.1568x; 5.1568x over previous
//
#include <hip/hip_runtime.h>
#include <math.h>

typedef unsigned short u16;
typedef unsigned int u32;

constexpr int kB = 16, kL = 512, kS = 1024, kD = 512, kM = 64;

typedef __attribute__((ext_vector_type(8))) short bf16x8;
typedef __attribute__((ext_vector_type(4))) float f32x4;

__device__ __forceinline__ float bf2f(u16 u) {
    union { u32 i; float f; } v; v.i = ((u32)u) << 16; return v.f;
}
__device__ __forceinline__ u16 f2bf(float f) {
    union { float f; u32 i; } v; v.f = f;
    u32 r = (v.i + 0x7FFFu + ((v.i >> 16) & 1u)) >> 16;
    return (u16)r;
}

// ---------------------------------------------------------------------------
// Plain bf16 MFMA GEMM: C[r,n] = op( sum_k A[r,k]*W[n,k] + bias + resid )
// A: R x K bf16 row-major; W: N x K bf16 row-major (X @ W.T).
// 128x128 tile, BK=64, 256 thr (4 waves 2x2), wave = 64x64 via 4x4 16x16x32.
// flags: 1=relu, 8=write bf16 Cbf, 16=write f32 Cout
// ---------------------------------------------------------------------------
__global__ __launch_bounds__(256, 2) void gemm_bf16(
    const u16* __restrict__ Abase, const u16* __restrict__ Wbase,
    const float* __restrict__ bias, const float* __restrict__ resid,
    float* __restrict__ Cout, u16* __restrict__ Cbf,
    int R, int N, int K, int flags)
{
    __shared__ __attribute__((aligned(16))) u16 Abuf[128 * 64];
    __shared__ __attribute__((aligned(16))) u16 Bbuf[128 * 64];
    const int tid = threadIdx.x;
    const int lane = tid & 63;
    const int wave = tid >> 6;
    const int wr = wave >> 1, wc = wave & 1;
    const int ln15 = lane & 15, lq = lane >> 4;
    const int r0 = blockIdx.y * 128, n0 = blockIdx.x * 128;

    f32x4 acc[4][4];
#pragma unroll
    for (int m = 0; m < 4; ++m)
#pragma unroll
        for (int n = 0; n < 4; ++n) acc[m][n] = (f32x4){0.f, 0.f, 0.f, 0.f};

    for (int k0 = 0; k0 < K; k0 += 64) {
        bf16x8 av[4], bv[4];
#pragma unroll
        for (int it = 0; it < 4; ++it) {
            int c = it * 256 + tid;
            int row = c >> 3, j = c & 7;
            int jj = j ^ (row & 7);
            av[it] = *(const bf16x8*)(Abase + (size_t)(r0 + row) * K + k0 + jj * 8);
            bv[it] = *(const bf16x8*)(Wbase + (size_t)(n0 + row) * K + k0 + jj * 8);
        }
        __syncthreads();
#pragma unroll
        for (int it = 0; it < 4; ++it) {
            int c = it * 256 + tid;
            int row = c >> 3, j = c & 7;
            *(bf16x8*)&Abuf[row * 64 + j * 8] = av[it];
            *(bf16x8*)&Bbuf[row * 64 + j * 8] = bv[it];
        }
        __syncthreads();
#pragma unroll
        for (int h = 0; h < 2; ++h) {
            int kg = lq + h * 4;
            bf16x8 af[4], bfv[4];
#pragma unroll
            for (int m = 0; m < 4; ++m) {
                int row = wr * 64 + m * 16 + ln15;
                af[m] = *(const bf16x8*)&Abuf[row * 64 + ((kg ^ (row & 7)) << 3)];
            }
#pragma unroll
            for (int n = 0; n < 4; ++n) {
                int col = wc * 64 + n * 16 + ln15;
                bfv[n] = *(const bf16x8*)&Bbuf[col * 64 + ((kg ^ (col & 7)) << 3)];
            }
#pragma unroll
            for (int m = 0; m < 4; ++m)
#pragma unroll
                for (int n = 0; n < 4; ++n)
                    acc[m][n] = __builtin_amdgcn_mfma_f32_16x16x32_bf16(af[m], bfv[n], acc[m][n], 0, 0, 0);
        }
        __syncthreads();
    }

#pragma unroll
    for (int m = 0; m < 4; ++m) {
#pragma unroll
        for (int n = 0; n < 4; ++n) {
            int gc = n0 + wc * 64 + n * 16 + ln15;
            float bv_ = bias ? bias[gc] : 0.f;
#pragma unroll
            for (int rg = 0; rg < 4; ++rg) {
                int gr = r0 + wr * 64 + m * 16 + lq * 4 + rg;
                float val = acc[m][n][rg] + bv_;
                if (resid) val += resid[(size_t)gr * N + gc];
                if (flags & 1) val = fmaxf(val, 0.f);
                if (flags & 16) Cout[(size_t)gr * N + gc] = val;
                if (flags & 8)  Cbf[(size_t)gr * N + gc] = f2bf(val);
            }
        }
    }
}

// ---------------------------------------------------------------------------
// Split-precision GEMM (~fp32 accuracy): A, W are fp32; each split to hi/lo
// bf16; acc += ah*bh + ah*bl + al*bh (3 MFMAs). Same tile layout as gemm_bf16.
// flags: 1=relu, 4=conv-mode (K=4608; A = base of 3 fp32 T buffers;
//        W = PK[t][j][n][d] fp32), 8=write bf16 Cbf, 16=write f32 Cout
// ---------------------------------------------------------------------------
__global__ __launch_bounds__(256, 2) void gemm_f32s(
    const float* __restrict__ Abase, const float* __restrict__ Wbase,
    const float* __restrict__ bias, const float* __restrict__ resid,
    float* __restrict__ Cout, u16* __restrict__ Cbf,
    int R, int N, int K, int flags)
{
    __shared__ __attribute__((aligned(16))) u16 Ah[128 * 64];
    __shared__ __attribute__((aligned(16))) u16 Al[128 * 64];
    __shared__ __attribute__((aligned(16))) u16 Bh[128 * 64];
    __shared__ __attribute__((aligned(16))) u16 Bl[128 * 64];
    const int tid = threadIdx.x;
    const int lane = tid & 63;
    const int wave = tid >> 6;
    const int wr = wave >> 1, wc = wave & 1;
    const int ln15 = lane & 15, lq = lane >> 4;
    const int r0 = blockIdx.y * 128, n0 = blockIdx.x * 128;

    f32x4 acc[4][4];
#pragma unroll
    for (int m = 0; m < 4; ++m)
#pragma unroll
        for (int n = 0; n < 4; ++n) acc[m][n] = (f32x4){0.f, 0.f, 0.f, 0.f};

    for (int k0 = 0; k0 < K; k0 += 64) {
        int t = 0, jsh = 0, dk = k0;
        if (flags & 4) {
            t = k0 / 1536;
            int rem = k0 - t * 1536;
            jsh = rem >> 9;
            dk = rem & 511;
        }
        bf16x8 avh[4], avl[4], bvh[4], bvl[4];
#pragma unroll
        for (int it = 0; it < 4; ++it) {
            int c = it * 256 + tid;
            int row = c >> 3, j = c & 7;
            int jj = j ^ (row & 7);
            size_t aoff, boff;
            int grow = r0 + row;
            int gcol = n0 + row;
            if (flags & 4) {
                int b_ = grow >> 9, l_ = grow & 511;
                int sr = (b_ << 9) | ((l_ + jsh + 511) & 511);
                aoff = (size_t)t * (size_t)(kB * kL * kD) + (size_t)sr * 512 + dk + jj * 8;
                boff = (((size_t)(t * 3 + jsh) * 512) + gcol) * 512 + dk + jj * 8;
            } else {
                aoff = (size_t)grow * K + k0 + jj * 8;
                boff = (size_t)gcol * K + k0 + jj * 8;
            }
            float4 a0 = *(const float4*)(Abase + aoff);
            float4 a1 = *(const float4*)(Abase + aoff + 4);
            float4 b0 = *(const float4*)(Wbase + boff);
            float4 b1 = *(const float4*)(Wbase + boff + 4);
            float fa[8] = {a0.x, a0.y, a0.z, a0.w, a1.x, a1.y, a1.z, a1.w};
            float fb[8] = {b0.x, b0.y, b0.z, b0.w, b1.x, b1.y, b1.z, b1.w};
#pragma unroll
            for (int e = 0; e < 8; ++e) {
                u16 h = f2bf(fa[e]);
                avh[it][e] = (short)h;
                avl[it][e] = (short)f2bf(fa[e] - bf2f(h));
                u16 g = f2bf(fb[e]);
                bvh[it][e] = (short)g;
                bvl[it][e] = (short)f2bf(fb[e] - bf2f(g));
            }
        }
        __syncthreads();
#pragma unroll
        for (int it = 0; it < 4; ++it) {
            int c = it * 256 + tid;
            int row = c >> 3, j = c & 7;
            int o = row * 64 + j * 8;
            *(bf16x8*)&Ah[o] = avh[it];
            *(bf16x8*)&Al[o] = avl[it];
            *(bf16x8*)&Bh[o] = bvh[it];
            *(bf16x8*)&Bl[o] = bvl[it];
        }
        __syncthreads();
#pragma unroll
        for (int h = 0; h < 2; ++h) {
            int kg = lq + h * 4;
            bf16x8 afh[4], afl[4], bfh[4], bfl[4];
#pragma unroll
            for (int m = 0; m < 4; ++m) {
                int row = wr * 64 + m * 16 + ln15;
                int o = row * 64 + ((kg ^ (row & 7)) << 3);
                afh[m] = *(const bf16x8*)&Ah[o];
                afl[m] = *(const bf16x8*)&Al[o];
            }
#pragma unroll
            for (int n = 0; n < 4; ++n) {
                int col = wc * 64 + n * 16 + ln15;
                int o = col * 64 + ((kg ^ (col & 7)) << 3);
                bfh[n] = *(const bf16x8*)&Bh[o];
                bfl[n] = *(const bf16x8*)&Bl[o];
            }
#pragma unroll
            for (int m = 0; m < 4; ++m)
#pragma unroll
                for (int n = 0; n < 4; ++n) {
                    acc[m][n] = __builtin_amdgcn_mfma_f32_16x16x32_bf16(afh[m], bfh[n], acc[m][n], 0, 0, 0);
                    acc[m][n] = __builtin_amdgcn_mfma_f32_16x16x32_bf16(afh[m], bfl[n], acc[m][n], 0, 0, 0);
                    acc[m][n] = __builtin_amdgcn_mfma_f32_16x16x32_bf16(afl[m], bfh[n], acc[m][n], 0, 0, 0);
                }
        }
        __syncthreads();
    }

#pragma unroll
    for (int m = 0; m < 4; ++m) {
#pragma unroll
        for (int n = 0; n < 4; ++n) {
            int gc = n0 + wc * 64 + n * 16 + ln15;
            float bv_ = bias ? bias[gc] : 0.f;
#pragma unroll
            for (int rg = 0; rg < 4; ++rg) {
                int gr = r0 + wr * 64 + m * 16 + lq * 4 + rg;
                float val = acc[m][n][rg] + bv_;
                if (resid) val += resid[(size_t)gr * N + gc];
                if (flags & 1) val = fmaxf(val, 0.f);
                if (flags & 16) Cout[(size_t)gr * N + gc] = val;
                if (flags & 8)  Cbf[(size_t)gr * N + gc] = f2bf(val);
            }
        }
    }
}

// ---------------------------------------------------------------------------
// Twiddle tables: tw[(mg*N + l)*8 + mm*2 + {0:cos,1:-sin}], modes m = mg*4+mm
// ---------------------------------------------------------------------------
__global__ void twiddle_gen(float* __restrict__ tw, int N)
{
    int idx = blockIdx.x * 256 + threadIdx.x;
    if (idx >= 16 * N * 4) return;
    int mg = idx / (N * 4);
    int rem = idx - mg * N * 4;
    int l = rem >> 2, mm = rem & 3;
    int m = mg * 4 + mm;
    int ph = (int)(((long long)m * (long long)l) % N);
    float ang = 6.283185307179586f * (float)ph / (float)N;
    float s_, c_;
    sincosf(ang, &s_, &c_);
    tw[((size_t)mg * N + l) * 8 + mm * 2 + 0] = c_;
    tw[((size_t)mg * N + l) * 8 + mm * 2 + 1] = -s_;
}

// ---------------------------------------------------------------------------
// Forward DFT, first 64 modes, table-driven, fp32 input.
// Output normal (B,64,D) or transposed [d][b][m].
// ---------------------------------------------------------------------------
__global__ __launch_bounds__(512) void dft_fwd2(
    const float* __restrict__ Ain, const float* __restrict__ tw,
    float* __restrict__ Fr, float* __restrict__ Fi, int N, int transposed)
{
    __shared__ float twl[8192];
    const int blk = blockIdx.x;
    const int b = blk >> 4, mg = blk & 15;
    const int m0 = mg * 4;
    const int tid = threadIdx.x;
    for (int idx = tid; idx < N * 8; idx += 512)
        twl[idx] = tw[(size_t)mg * N * 8 + idx];
    __syncthreads();

    const int d = tid;
    float fr0 = 0, fi0 = 0, fr1 = 0, fi1 = 0, fr2 = 0, fi2 = 0, fr3 = 0, fi3 = 0;
    const float* A32 = Ain + (size_t)b * N * kD + d;
    for (int l = 0; l < N; ++l) {
        float a = A32[(size_t)l * kD];
        float4 t0 = *(const float4*)&twl[l * 8];
        float4 t1 = *(const float4*)&twl[l * 8 + 4];
        fr0 += a * t0.x; fi0 += a * t0.y;
        fr1 += a * t0.z; fi1 += a * t0.w;
        fr2 += a * t1.x; fi2 += a * t1.y;
        fr3 += a * t1.z; fi3 += a * t1.w;
    }
    if (transposed) {
        size_t base = ((size_t)d * kB + b) * kM + m0;
        Fr[base + 0] = fr0; Fr[base + 1] = fr1; Fr[base + 2] = fr2; Fr[base + 3] = fr3;
        Fi[base + 0] = fi0; Fi[base + 1] = fi1; Fi[base + 2] = fi2; Fi[base + 3] = fi3;
    } else {
        size_t base = ((size_t)b * kM + m0) * kD + d;
        Fr[base] = fr0; Fr[base + 512] = fr1; Fr[base + 1024] = fr2; Fr[base + 1536] = fr3;
        Fi[base] = fi0; Fi[base + 512] = fi1; Fi[base + 1024] = fi2; Fi[base + 1536] = fi3;
    }
}

// ---------------------------------------------------------------------------
// FEB per-mode contraction, d-chunked partials (occupancy fix from round 1).
// ---------------------------------------------------------------------------
__global__ __launch_bounds__(256) void feb_part(
    const float* __restrict__ qtr, const float* __restrict__ qti,
    const float* __restrict__ wr, const float* __restrict__ wi,
    float* __restrict__ part)
{
    __shared__ float sqr[4][16][64], sqi[4][16][64];
    const int eb = blockIdx.x;
    const int ch = blockIdx.y;
    const int tid = threadIdx.x;
    const int mm = tid & 63, ee = tid >> 6;
    const int e = eb * 4 + ee;
    float ar[16], ai[16];
#pragma unroll
    for (int b_ = 0; b_ < 16; ++b_) { ar[b_] = 0.f; ai[b_] = 0.f; }

    const int dbeg = ch * 128, dend = dbeg + 128;
    for (int d0 = dbeg; d0 < dend; d0 += 4) {
        __syncthreads();
#pragma unroll
        for (int rep = 0; rep < 16; ++rep) {
            int idx = tid + rep * 256;
            int m_ = idx & 63, b_ = (idx >> 6) & 15, dd_ = idx >> 10;
            size_t g = ((size_t)(d0 + dd_) * kB + b_) * kM + m_;
            sqr[dd_][b_][m_] = qtr[g];
            sqi[dd_][b_][m_] = qti[g];
        }
        __syncthreads();
#pragma unroll
        for (int dd = 0; dd < 4; ++dd) {
            size_t wofs = ((size_t)(d0 + dd) * kD + e) * kM + mm;
            float wrv = wr[wofs], wiv = wi[wofs];
#pragma unroll
            for (int b_ = 0; b_ < 16; ++b_) {
                float qr = sqr[dd][b_][mm], qi = sqi[dd][b_][mm];
                ar[b_] += qr * wrv - qi * wiv;
                ai[b_] += qr * wiv + qi * wrv;
            }
        }
    }
    float* reg = part + (size_t)(ch * 128 + eb) * 8192;
#pragma unroll
    for (int b_ = 0; b_ < 16; ++b_) {
        reg[(b_ * 64 + mm) * 4 + ee] = ar[b_];
        reg[4096 + (b_ * 64 + mm) * 4 + ee] = ai[b_];
    }
}

__global__ __launch_bounds__(256) void feb_reduce(
    const float* __restrict__ part, float* __restrict__ omr, float* __restrict__ omi)
{
    int idx = blockIdx.x * 256 + threadIdx.x;   // 0..524287
    int e = idx & 511, bm = idx >> 9;
    int eb = e >> 2, ee = e & 3;
    float r = 0.f, im = 0.f;
#pragma unroll
    for (int ch = 0; ch < 4; ++ch) {
        const float* reg = part + (size_t)(ch * 128 + eb) * 8192 + (bm * 4 + ee);
        r += reg[0];
        im += reg[4096];
    }
    omr[idx] = r;
    omi[idx] = im;
}

// ---------------------------------------------------------------------------
// Inverse real DFT (modes 0..63 -> length 512), numpy irfft semantics.
// ---------------------------------------------------------------------------
__global__ __launch_bounds__(512) void irdft(
    const float* __restrict__ omr, const float* __restrict__ omi,
    const float* __restrict__ resid, float* __restrict__ out, u16* __restrict__ out_bf)
{
    __shared__ float tc[64][16], tsn[64][16];
    const int blk = blockIdx.x;
    const int b = blk >> 5;
    const int l0 = (blk & 31) << 4;
    const int tid = threadIdx.x;

    for (int idx = tid; idx < 1024; idx += 512) {
        int m_ = idx >> 4, ll = idx & 15;
        int ph = (m_ * (l0 + ll)) & 511;
        float ang = 6.283185307179586f * (float)ph / 512.0f;
        float s_, c_;
        sincosf(ang, &s_, &c_);
        tc[m_][ll] = c_; tsn[m_][ll] = s_;
    }
    __syncthreads();

    const int e = tid;
    float acc[16];
    float r0 = omr[((size_t)b * kM) * kD + e];
#pragma unroll
    for (int ll = 0; ll < 16; ++ll) acc[ll] = r0;
    for (int m_ = 1; m_ < 64; ++m_) {
        float r = 2.f * omr[((size_t)b * kM + m_) * kD + e];
        float i_ = 2.f * omi[((size_t)b * kM + m_) * kD + e];
#pragma unroll
        for (int ll = 0; ll < 16; ++ll) acc[ll] += r * tc[m_][ll] - i_ * tsn[m_][ll];
    }
    const float inv = 1.0f / 512.0f;
#pragma unroll
    for (int ll = 0; ll < 16; ++ll) {
        size_t o = ((size_t)b * kL + l0 + ll) * kD + e;
        float v = acc[ll] * inv;
        if (resid) v += resid[o];
        if (out) out[o] = v;
        if (out_bf) out_bf[o] = f2bf(v);
    }
}

// ---------------------------------------------------------------------------
// Spectral cross attention, one block per (b,h). fp32.
// ---------------------------------------------------------------------------
__global__ __launch_bounds__(256) void spectral_attn(
    const float* __restrict__ qfr, const float* __restrict__ qfi,
    const float* __restrict__ kfr, const float* __restrict__ kfi,
    const float* __restrict__ vfr, const float* __restrict__ vfi,
    float* __restrict__ omr, float* __restrict__ omi)
{
    __shared__ float kr[64][65], ki[64][65], sat[64][65];
    const int b = blockIdx.x >> 3, h = blockIdx.x & 7;
    const int tid = threadIdx.x;
    const int dbase = h * 64;

    for (int idx = tid; idx < 4096; idx += 256) {
        int j = idx >> 6, dd = idx & 63;
        kr[j][dd] = kfr[((size_t)b * kM + j) * kD + dbase + dd];
        ki[j][dd] = kfi[((size_t)b * kM + j) * kD + dbase + dd];
    }
    __syncthreads();

    const int i_ = tid >> 2, jg = tid & 3;
    float s[16];
#pragma unroll
    for (int jj = 0; jj < 16; ++jj) s[jj] = 0.f;
    const float* qrp = qfr + ((size_t)b * kM + i_) * kD + dbase;
    const float* qip = qfi + ((size_t)b * kM + i_) * kD + dbase;
    for (int dd = 0; dd < 64; ++dd) {
        float qr = qrp[dd], qi = qip[dd];
#pragma unroll
        for (int jj = 0; jj < 16; ++jj) {
            int j = jg * 16 + jj;
            s[jj] += qr * kr[j][dd] + qi * ki[j][dd];
        }
    }
    float mx = s[0];
#pragma unroll
    for (int jj = 1; jj < 16; ++jj) mx = fmaxf(mx, s[jj]);
    mx = fmaxf(mx, __shfl_xor(mx, 1));
    mx = fmaxf(mx, __shfl_xor(mx, 2));
    float sum = 0.f;
#pragma unroll
    for (int jj = 0; jj < 16; ++jj) { s[jj] = expf(s[jj] - mx); sum += s[jj]; }
    sum += __shfl_xor(sum, 1);
    sum += __shfl_xor(sum, 2);
    float rinv = 1.0f / sum;
#pragma unroll
    for (int jj = 0; jj < 16; ++jj) sat[i_][jg * 16 + jj] = s[jj] * rinv;
    __syncthreads();

    const int dd = tid & 63, ig = tid >> 6;
    float ar[16], ai[16];
#pragma unroll
    for (int ii = 0; ii < 16; ++ii) { ar[ii] = 0.f; ai[ii] = 0.f; }
    for (int j = 0; j < 64; ++j) {
        float vr = vfr[((size_t)b * kM + j) * kD + dbase + dd];
        float vi = vfi[((size_t)b * kM + j) * kD + dbase + dd];
#pragma unroll
        for (int ii = 0; ii < 16; ++ii) {
            float a = sat[ig * 16 + ii][j];
            ar[ii] += a * vr;
            ai[ii] += a * vi;
        }
    }
#pragma unroll
    for (int ii = 0; ii < 16; ++ii) {
        size_t o = ((size_t)b * kM + ig * 16 + ii) * kD + dbase + dd;
        omr[o] = ar[ii];
        omi[o] = ai[ii];
    }
}

// ---------------------------------------------------------------------------
// MoE decomposition epilogue. Writes fp32 trend (for split conv GEMM).
// ---------------------------------------------------------------------------
__global__ __launch_bounds__(256) void decomp_apply(
    const float* __restrict__ x, const float* __restrict__ logits,
    float* __restrict__ xout, u16* __restrict__ xout_bf, float* __restrict__ tout)
{
    int idx = blockIdx.x * 256 + threadIdx.x;
    if (idx >= kB * kL * kD) return;
    int d = idx & 511;
    int l = (idx >> 9) & 511;
    int b = idx >> 18;
    const float* lg = logits + ((size_t)b * kL + l) * 3;
    float g0 = lg[0], g1 = lg[1], g2 = lg[2];
    float m = fmaxf(g0, fmaxf(g1, g2));
    float e0 = expf(g0 - m), e1 = expf(g1 - m), e2 = expf(g2 - m);
    float inv = 1.0f / (e0 + e1 + e2);
    g0 = e0 * inv; g1 = e1 * inv; g2 = e2 * inv;

    const float* xb = x + (size_t)b * kL * kD + d;
    float v[7];
#pragma unroll
    for (int j = 0; j < 7; ++j) {
        int ls = l + j - 3;
        v[j] = (ls >= 0 && ls < kL) ? xb[(size_t)ls * kD] : 0.f;
    }
    float s3 = (v[2] + v[3] + v[4]) * (1.0f / 3.0f);
    float s5 = (v[1] + v[2] + v[3] + v[4] + v[5]) * 0.2f;
    float s7 = (v[0] + v[1] + v[2] + v[3] + v[4] + v[5] + v[6]) * (1.0f / 7.0f);
    float trend = g0 * s3 + g1 * s5 + g2 * s7;
    float res = v[3] - trend;
    if (xout) xout[idx] = res;
    if (xout_bf) xout_bf[idx] = f2bf(res);
    tout[idx] = trend;
}

// ---------------------------------------------------------------------------
// Gate layer 2: logits[r][n] = b2[n] + sum_c GH[r,c]*w2[n,c]  (N=3, K=256)
// ---------------------------------------------------------------------------
__global__ __launch_bounds__(256) void gate2(
    const u16* __restrict__ GH, const float* __restrict__ w2,
    const float* __restrict__ b2, float* __restrict__ logits)
{
    __shared__ float w2l[3][256];
    int tid = threadIdx.x;
    for (int i = tid; i < 768; i += 256) w2l[i >> 8][i & 255] = w2[i];
    __syncthreads();
    int r = blockIdx.x * 256 + tid;
    float s0 = b2[0], s1 = b2[1], s2 = b2[2];
    const u16* g = GH + (size_t)r * 256;
    for (int c0 = 0; c0 < 256; c0 += 8) {
        uint4 u = *(const uint4*)&g[c0];
        u32 w[4] = {u.x, u.y, u.z, u.w};
#pragma unroll
        for (int p = 0; p < 4; ++p) {
            float f0 = bf2f((u16)(w[p] & 0xFFFF));
            float f1 = bf2f((u16)(w[p] >> 16));
            int c = c0 + p * 2;
            s0 += f0 * w2l[0][c] + f1 * w2l[0][c + 1];
            s1 += f0 * w2l[1][c] + f1 * w2l[1][c + 1];
            s2 += f0 * w2l[2][c] + f1 * w2l[2][c + 1];
        }
    }
    logits[(size_t)r * 3 + 0] = s0;
    logits[(size_t)r * 3 + 1] = s1;
    logits[(size_t)r * 3 + 2] = s2;
}

// ---------------------------------------------------------------------------
__global__ void cast_f32_bf16(const float* __restrict__ src, u16* __restrict__ dst, int n)
{
    int idx = (blockIdx.x * 256 + threadIdx.x) * 4;
    if (idx >= n) return;
    float4 v = *(const float4*)&src[idx];
    ushort4 o;
    o.x = f2bf(v.x); o.y = f2bf(v.y); o.z = f2bf(v.z); o.w = f2bf(v.w);
    *(ushort4*)&dst[idx] = o;
}

// Repack conv weights p[o,d,j] -> pk[t][j][o][d] (fp32)
__global__ void repack_p(const float* __restrict__ p1, const float* __restrict__ p2,
                         const float* __restrict__ p3, float* __restrict__ pk)
{
    int idx = blockIdx.x * 256 + threadIdx.x;
    if (idx >= 3 * 3 * 512 * 512) return;
    int d = idx & 511;
    int oc = (idx >> 9) & 511;
    int j = (idx / (512 * 512)) % 3;
    int t = idx / (3 * 512 * 512);
    const float* p = (t == 0) ? p1 : (t == 1) ? p2 : p3;
    pk[idx] = p[(size_t)oc * 512 * 3 + (size_t)d * 3 + j];
}

// ---------------------------------------------------------------------------
extern "C" void kernel_launch(void* const* d_in, const int* in_sizes, int n_in,
                              void* d_out, int out_size, void* d_ws, size_t ws_size,
                              hipStream_t stream)
{
    const float* x_in   = (const float*)d_in[0];
    const float* cross  = (const float*)d_in[1];
    const float* feb_wr = (const float*)d_in[2];
    const float* feb_wi = (const float*)d_in[3];
    const float* wq = (const float*)d_in[4];
    const float* bq = (const float*)d_in[5];
    const float* wk = (const float*)d_in[6];
    const float* bk = (const float*)d_in[7];
    const float* wv = (const float*)d_in[8];
    const float* bv = (const float*)d_in[9];
    const float* wo = (const float*)d_in[10];
    const float* bo = (const float*)d_in[11];
    const float* w_ff1 = (const float*)d_in[12];
    const float* w_ff2 = (const float*)d_in[13];
    const float* d1_w1 = (const float*)d_in[14];
    const float* d1_b1 = (const float*)d_in[15];
    const float* d1_w2 = (const float*)d_in[16];
    const float* d1_b2 = (const float*)d_in[17];
    const float* d2_w1 = (const float*)d_in[18];
    const float* d2_b1 = (const float*)d_in[19];
    const float* d2_w2 = (const float*)d_in[20];
    const float* d2_b2 = (const float*)d_in[21];
    const float* d3_w1 = (const float*)d_in[22];
    const float* d3_b1 = (const float*)d_in[23];
    const float* d3_w2 = (const float*)d_in[24];
    const float* d3_b2 = (const float*)d_in[25];
    const float* p1 = (const float*)d_in[26];
    const float* p2 = (const float*)d_in[27];
    const float* p3 = (const float*)d_in[28];

    // workspace layout (floats), peak 46,030,848 floats = 184.1 MB
    float* ws = (float*)d_ws;
    float* X    = ws;                     // 4,194,304
    float* XT   = ws + 4194304;           // 4,194,304
    float* Kf   = ws + 8388608;           // 8,388,608 (FEBP overlay A; HIDbf overlay E)
    float* Vf   = ws + 16777216;          // 8,388,608 (PKf overlay G)
    float* T1f  = ws + 25165824;          // 4,194,304 (T1,T2,T3 contiguous)
    float* T2f  = ws + 29360128;          // 4,194,304
    float* T3f  = ws + 33554432;          // 4,194,304 (Q0f/Qf overlay in phase C)
    float* QFR  = ws + 37748736;          // 8 x 524,288
    float* QFI  = QFR + 524288;
    float* KFR  = QFI + 524288;
    float* KFI  = KFR + 524288;
    float* VFR  = KFI + 524288;
    float* VFI  = VFR + 524288;
    float* OMR  = VFI + 524288;
    float* OMI  = OMR + 524288;
    u16*  GHb   = (u16*)(ws + 41943040);  // 2,097,152 u16
    float* GLG  = ws + 42991616;          // 24,576
    u16*  Xbf   = (u16*)(ws + 43016192);  // 4,194,304 u16
    u16*  ff2b  = (u16*)(ws + 45113344);  // 1,048,576 u16
    u16*  d1w1b = (u16*)(ws + 45637632);  // 131,072 u16
    u16*  d2w1b = (u16*)(ws + 45703168);
    u16*  d3w1b = (u16*)(ws + 45768704);
    float* TW512  = ws + 45834240;        // 65,536
    float* TW1024 = ws + 45899776;        // 131,072  -> end 46,030,848
    float* FEBP = Kf;                     // phase A overlay
    u16*  HIDbf = (u16*)Kf;               // phase E overlay (16,777,216 u16)
    float* PKf  = Vf;                     // phase G overlay (2,359,296 f32)
    float* Q0f  = T3f;                    // phase C overlay
    float* Qf   = T3f;

    float* outx = (float*)d_out;
    float* outt = outx + 4194304;

    auto gemmb = [&](const u16* A, const u16* W, const float* bias, const float* resid,
                     float* C, u16* Cb, int R, int N, int K, int flags) {
        dim3 g(N / 128, R / 128);
        hipLaunchKernelGGL(gemm_bf16, g, dim3(256), 0, stream, A, W, bias, resid, C, Cb, R, N, K, flags);
    };
    auto gemms = [&](const float* A, const float* W, const float* bias, const float* resid,
                     float* C, u16* Cb, int R, int N, int K, int flags) {
        dim3 g(N / 128, R / 128);
        hipLaunchKernelGGL(gemm_f32s, g, dim3(256), 0, stream, A, W, bias, resid, C, Cb, R, N, K, flags);
    };
    auto cast = [&](const float* s, u16* d, int n) {
        hipLaunchKernelGGL(cast_f32_bf16, dim3(n / 1024), dim3(256), 0, stream, s, d, n);
    };

    // ---- Prep ----
    cast(w_ff2, ff2b, 1048576);
    cast(d1_w1, d1w1b, 131072);
    cast(d2_w1, d2w1b, 131072);
    cast(d3_w1, d3w1b, 131072);
    hipLaunchKernelGGL(twiddle_gen, dim3(128), dim3(256), 0, stream, TW512, 512);
    hipLaunchKernelGGL(twiddle_gen, dim3(256), dim3(256), 0, stream, TW1024, 1024);

    // ---- Phase A: x = x + fourier_block(x) ----
    hipLaunchKernelGGL(dft_fwd2, dim3(256), dim3(512), 0, stream, x_in, TW512, QFR, QFI, 512, 1);
    hipLaunchKernelGGL(feb_part, dim3(128, 4), dim3(256), 0, stream, QFR, QFI, feb_wr, feb_wi, FEBP);
    hipLaunchKernelGGL(feb_reduce, dim3(2048), dim3(256), 0, stream, FEBP, OMR, OMI);
    hipLaunchKernelGGL(irdft, dim3(512), dim3(512), 0, stream, OMR, OMI, x_in, X, Xbf);

    // ---- Phase B: decomp1 ----
    gemmb(Xbf, d1w1b, d1_b1, nullptr, nullptr, GHb, 8192, 256, 512, 1 | 8);
    hipLaunchKernelGGL(gate2, dim3(32), dim3(256), 0, stream, GHb, d1_w2, d1_b2, GLG);
    hipLaunchKernelGGL(decomp_apply, dim3(16384), dim3(256), 0, stream, X, GLG, XT, (u16*)nullptr, T1f);

    // ---- Phase C: x = x + fourier_cross(x, cross); fp32 precision path ----
    gemms(XT, wq, bq, nullptr, Q0f, nullptr, 8192, 512, 512, 16);
    gemms(cross, wk, bk, nullptr, Kf, nullptr, 16384, 512, 512, 16);
    gemms(cross, wv, bv, nullptr, Vf, nullptr, 16384, 512, 512, 16);
    hipLaunchKernelGGL(dft_fwd2, dim3(256), dim3(512), 0, stream, Q0f, TW512, QFR, QFI, 512, 0);
    hipLaunchKernelGGL(dft_fwd2, dim3(256), dim3(512), 0, stream, Kf, TW1024, KFR, KFI, 1024, 0);
    hipLaunchKernelGGL(dft_fwd2, dim3(256), dim3(512), 0, stream, Vf, TW1024, VFR, VFI, 1024, 0);
    hipLaunchKernelGGL(repack_p, dim3(9216), dim3(256), 0, stream, p1, p2, p3, PKf);
    hipLaunchKernelGGL(spectral_attn, dim3(128), dim3(256), 0, stream,
                       QFR, QFI, KFR, KFI, VFR, VFI, OMR, OMI);
    hipLaunchKernelGGL(irdft, dim3(512), dim3(512), 0, stream,
                       OMR, OMI, (const float*)nullptr, Qf, (u16*)nullptr);
    gemms(Qf, wo, bo, XT, X, Xbf, 8192, 512, 512, 16 | 8);

    // ---- Phase D: decomp2 ----
    gemmb(Xbf, d2w1b, d2_b1, nullptr, nullptr, GHb, 8192, 256, 512, 1 | 8);
    hipLaunchKernelGGL(gate2, dim3(32), dim3(256), 0, stream, GHb, d2_w2, d2_b2, GLG);
    hipLaunchKernelGGL(decomp_apply, dim3(16384), dim3(256), 0, stream, X, GLG, XT, (u16*)nullptr, T2f);

    // ---- Phase E: FFN (FFN1 split fp32 from XT; FFN2 bf16) ----
    gemms(XT, w_ff1, nullptr, nullptr, nullptr, HIDbf, 8192, 2048, 512, 1 | 8);
    gemmb(HIDbf, ff2b, nullptr, XT, X, Xbf, 8192, 512, 2048, 16 | 8);

    // ---- Phase F: decomp3 -> d_out x ----
    gemmb(Xbf, d3w1b, d3_b1, nullptr, nullptr, GHb, 8192, 256, 512, 1 | 8);
    hipLaunchKernelGGL(gate2, dim3(32), dim3(256), 0, stream, GHb, d3_w2, d3_b2, GLG);
    hipLaunchKernelGGL(decomp_apply, dim3(16384), dim3(256), 0, stream, X, GLG, outx, (u16*)nullptr, T3f);

    // ---- Phase G: residual_trend, one K=4608 split GEMM over (t,j) ----
    gemms(T1f, PKf, nullptr, nullptr, outt, nullptr, 8192, 512, 4608, 4 | 16);

    (void)in_sizes; (void)n_in; (void)out_size; (void)ws_size;
}